// Round 3
// baseline (510.138 us; speedup 1.0000x reference)
//
#include <hip/hip_runtime.h>
#include <hip/hip_bf16.h>
#include <math.h>

// Problem constants (from reference)
#define NV    2048      // N
#define TT    128       // T tokens
#define TM1   127       // T-1 tensions
#define KK    20        // K = int(2048*0.01)
#define LRC   0.01f
#define EPSC  1e-8f
#define CHK   20        // j-chunk for LDS count table (ccur==20 in practice)

// Workspace layout (bytes):
//   0        int   act_idx[128*64]     (32768)
//   32768    int   act_cnt[128]        (512)
//   33280    int   occCnt[2048]        (8192)
//   41472    u8    occList[2048*128]   (262144)
//   303616   f32   ST0[2048*2048]      (16777216)   sigma transposed
// total 17,080,832 B

// ---------------------------------------------------------------------------
// Kernel 1: exact top-K threshold per token (per-wave extraction + 4-way
// merge — no serialized block rounds), activation lists, occurrence lists.
// ---------------------------------------------------------------------------
__global__ __launch_bounds__(256) void act_kernel(
    const int* __restrict__ tokens, const float* __restrict__ proj,
    int* __restrict__ act_idx, int* __restrict__ act_cnt,
    int* __restrict__ occCnt, unsigned char* __restrict__ occList)
{
    const int t    = blockIdx.x;       // 0..127
    const int tid  = threadIdx.x;      // 0..255
    const int lane = tid & 63;
    const int wid  = tid >> 6;

    const float* __restrict__ row = proj + (size_t)tokens[t] * (size_t)NV;

    // Wave w owns contiguous chunk [w*512, w*512+512); coalesced 256B loads.
    float v[8];
    #pragma unroll
    for (int r = 0; r < 8; ++r) v[r] = row[wid * 512 + r * 64 + lane];

    __shared__ float wcand[4][KK];
    __shared__ float thrS;
    __shared__ int   idxLDS[64];
    __shared__ int   cntS;

    // Per-wave top-20 extraction: butterfly max, kill one instance per round.
    for (int it = 0; it < KK; ++it) {
        float lm = v[0];
        #pragma unroll
        for (int r = 1; r < 8; ++r) lm = fmaxf(lm, v[r]);
        #pragma unroll
        for (int off = 1; off < 64; off <<= 1) lm = fmaxf(lm, __shfl_xor(lm, off));
        // lm = wave max, on all lanes
        bool has = false;
        #pragma unroll
        for (int r = 0; r < 8; ++r) has = has || (v[r] == lm);
        const unsigned long long m = __ballot(has);
        if (lane == (int)(__ffsll((long long)m) - 1)) {
            bool done = false;
            #pragma unroll
            for (int r = 0; r < 8; ++r)
                if (!done && v[r] == lm) { v[r] = -__builtin_inff(); done = true; }
        }
        if (lane == 0) wcand[wid][it] = lm;
    }
    __syncthreads();

    // Merge the four descending 20-lists: 20th pick = global 20th largest.
    if (tid == 0) {
        int p0 = 0, p1 = 0, p2 = 0, p3 = 0;
        float th = 0.0f;
        for (int k = 0; k < KK; ++k) {
            float bv = -__builtin_inff(); int bw = 0;
            if (p0 < KK && wcand[0][p0] > bv) { bv = wcand[0][p0]; bw = 0; }
            if (p1 < KK && wcand[1][p1] > bv) { bv = wcand[1][p1]; bw = 1; }
            if (p2 < KK && wcand[2][p2] > bv) { bv = wcand[2][p2]; bw = 2; }
            if (p3 < KK && wcand[3][p3] > bv) { bv = wcand[3][p3]; bw = 3; }
            if      (bw == 0) ++p0;
            else if (bw == 1) ++p1;
            else if (bw == 2) ++p2;
            else              ++p3;
            th = bv;
        }
        thrS = th;
    }
    __syncthreads();
    const float thr = thrS;

    // Deterministic ordered compaction (wave 0); row is L1/L2-hot.
    if (wid == 0) {
        int base = 0;
        for (int round = 0; round < NV / 64; ++round) {
            const int i = round * 64 + lane;
            const bool p = (row[i] >= thr);
            const unsigned long long mm = __ballot(p);
            const int pos = base + (int)__popcll(mm & ((1ull << lane) - 1ull));
            if (p && pos < 64) idxLDS[pos] = i;
            base += (int)__popcll(mm);
        }
        if (lane == 0) cntS = base < 64 ? base : 64;
    }
    __syncthreads();
    const int cnt = cntS;
    if (tid == 0) act_cnt[t] = cnt;
    if (tid < cnt) {
        const int j = idxLDS[tid];
        act_idx[t * 64 + tid] = j;
        const int slot = atomicAdd(&occCnt[j], 1);
        occList[j * 128 + slot] = (unsigned char)t;
    }
}

// ---------------------------------------------------------------------------
// Kernel 2: ST0[j][i] = sigma[i][j]
// ---------------------------------------------------------------------------
__global__ __launch_bounds__(256) void transpose_kernel(
    const float* __restrict__ in, float* __restrict__ out)
{
    __shared__ float tile[32][33];
    const int tx = threadIdx.x;       // 0..31
    const int ty = threadIdx.y;       // 0..7
    const int x0 = blockIdx.x * 32;
    const int y0 = blockIdx.y * 32;
    #pragma unroll
    for (int k = 0; k < 4; ++k)
        tile[ty + k * 8][tx] = in[(size_t)(y0 + ty + k * 8) * NV + x0 + tx];
    __syncthreads();
    #pragma unroll
    for (int k = 0; k < 4; ++k)
        out[(size_t)(x0 + ty + k * 8) * NV + y0 + tx] = tile[tx][ty + k * 8];
}

// ---------------------------------------------------------------------------
// Kernel 3: one block per step t. Flat count accumulation (packed u16 in
// LDS, no per-j serialization), deterministic i-major apply.
//   pred[i] = sum_{j in A_t} min(1, sigma0[i][j] + LR*c_t(i,j))
//   c_t(i,j) = #{s < t : j in A_s, i in A_{s+1}}   (<= 127, fits u16)
// ---------------------------------------------------------------------------
__global__ __launch_bounds__(512) void tension_kernel(
    const float* __restrict__ sigma0, const float* __restrict__ ST0,
    const int* __restrict__ act_idx, const int* __restrict__ act_cnt,
    const int* __restrict__ occCnt, const unsigned char* __restrict__ occList,
    const int* __restrict__ plast, float* __restrict__ out)
{
    const int t    = blockIdx.x;       // 0..126
    const int tid  = threadIdx.x;      // 0..511
    const int lane = tid & 63;
    const int wid  = tid >> 6;

    __shared__ float        predS[NV];              // 8 KB
    __shared__ unsigned int cnt32[CHK * 1024];      // 80 KB: u16 counts packed 2/word
    __shared__ int          acur[64], anext[64];
    __shared__ float        wsum[8];

    const int ccur  = act_cnt[t];
    const int cnext = act_cnt[t + 1];
    if (tid < 64) {
        acur[tid]  = act_idx[t * 64 + tid];
        anext[tid] = act_idx[(t + 1) * 64 + tid];
    }
    __syncthreads();

    // Base pred from original sigma: coalesced row reads of ST0.
    // (Same association as the verified absmax-0 version: ascending jj.)
    float acc[4] = {0.f, 0.f, 0.f, 0.f};
    for (int jj = 0; jj < ccur; ++jj) {
        const float* __restrict__ rowp = ST0 + (size_t)acur[jj] * NV;
        #pragma unroll
        for (int r = 0; r < 4; ++r) acc[r] += rowp[r * 512 + tid];
    }

    float dsum[4] = {0.f, 0.f, 0.f, 0.f};
    const bool plas = (plast[0] != 0);
    if (plas) {
        for (int jc = 0; jc < ccur; jc += CHK) {           // one chunk normally
            const int je = (jc + CHK < ccur) ? jc + CHK : ccur;
            for (int e = tid; e < (je - jc) * 1024; e += 512) cnt32[e] = 0u;
            __syncthreads();

            // Flat accumulation over all j in chunk — no intervening syncs.
            for (int jj = jc; jj < je; ++jj) {
                const int j    = acur[jj];
                const int oc   = occCnt[j];
                const int base = (jj - jc) * 1024;
                for (int p = tid; p < oc * 64; p += 512) {
                    const int o  = p >> 6;
                    const int ii = p & 63;
                    const int s  = (int)occList[j * 128 + o];
                    if (s < t) {
                        const int cs = act_cnt[s + 1];
                        if (ii < cs) {
                            const int i = act_idx[(s + 1) * 64 + ii];
                            atomicAdd(&cnt32[base + (i >> 1)],
                                      (i & 1) ? 65536u : 1u);
                        }
                    }
                }
            }
            __syncthreads();

            // Deterministic apply: per i, ascending jj (matches prior order).
            #pragma unroll
            for (int r = 0; r < 4; ++r) {
                const int i = r * 512 + tid;
                float ds = 0.f;
                for (int jj = jc; jj < je; ++jj) {
                    const unsigned w = cnt32[(jj - jc) * 1024 + (i >> 1)];
                    const unsigned c = (i & 1) ? (w >> 16) : (w & 0xffffu);
                    if (c) {
                        const float s0 = sigma0[(size_t)i * NV + acur[jj]];
                        ds += fminf(1.0f - s0, LRC * (float)c);
                    }
                }
                dsum[r] += ds;
            }
            __syncthreads();
        }
    }

    // Final pred into LDS
    #pragma unroll
    for (int r = 0; r < 4; ++r) {
        const int i = r * 512 + tid;
        predS[i] = acc[r] + dsum[r];
    }
    __syncthreads();

    // norm^2 reduce over all 2048
    float loc = 0.0f;
    #pragma unroll
    for (int r = 0; r < 4; ++r) { const float p = predS[r * 512 + tid]; loc += p * p; }
    #pragma unroll
    for (int off = 32; off; off >>= 1) loc += __shfl_down(loc, off);
    if (lane == 0) wsum[wid] = loc;
    __syncthreads();

    if (tid < 64) {
        float n2 = 0.0f;
        #pragma unroll
        for (int w = 0; w < 8; ++w) n2 += wsum[w];
        float d = (tid < cnext) ? predS[anext[tid]] : 0.0f;
        #pragma unroll
        for (int off = 32; off; off >>= 1) d += __shfl_down(d, off);
        if (tid == 0) {
            const float pn = sqrtf(n2);
            float tens;
            if (plas) {
                const float overlap = d / (pn * sqrtf((float)KK) + EPSC);
                tens = (pn > 0.0f) ? (1.0f - overlap) : 1.0f;
            } else {
                const float overlap = d / (pn * sqrtf((float)cnext) + EPSC);
                tens = 1.0f - overlap;
            }
            out[t] = tens;
        }
    }
}

// ---------------------------------------------------------------------------
extern "C" void kernel_launch(void* const* d_in, const int* in_sizes, int n_in,
                              void* d_out, int out_size, void* d_ws, size_t ws_size,
                              hipStream_t stream)
{
    const int*   tokens = (const int*)d_in[0];
    const float* proj   = (const float*)d_in[1];
    const float* sigma  = (const float*)d_in[2];
    const int*   plast  = (const int*)d_in[3];
    float*       out    = (float*)d_out;

    char* ws = (char*)d_ws;
    int*           act_idx = (int*)(ws + 0);
    int*           act_cnt = (int*)(ws + 32768);
    int*           occCnt  = (int*)(ws + 33280);
    unsigned char* occList = (unsigned char*)(ws + 41472);
    float*         ST0     = (float*)(ws + 303616);

    hipMemsetAsync(occCnt, 0, NV * sizeof(int), stream);
    act_kernel<<<TT, 256, 0, stream>>>(tokens, proj, act_idx, act_cnt, occCnt, occList);
    transpose_kernel<<<dim3(NV / 32, NV / 32), dim3(32, 8), 0, stream>>>(sigma, ST0);
    tension_kernel<<<TM1, 512, 0, stream>>>(sigma, ST0, act_idx, act_cnt, occCnt,
                                            occList, plast, out);
}

// Round 6
// 494.921 us; speedup vs baseline: 1.0307x; 1.0307x over previous
//
#include <hip/hip_runtime.h>
#include <hip/hip_bf16.h>
#include <math.h>

// Problem constants (from reference)
#define NV    2048      // N
#define TT    128       // T tokens
#define TM1   127       // T-1 tensions
#define KK    20        // K = int(2048*0.01)
#define LRC   0.01f
#define EPSC  1e-8f
#define CHK   20        // j-chunk for LDS count table (ccur==20 in practice)

// Workspace layout (bytes):
//   0        int   act_idx[128*64]     (32768)
//   32768    int   act_cnt[128]        (512)
//   33280    int   occCnt[2048]        (8192)
//   41472    u8    occList[2048*128]   (262144)
//   303616   f32   ST0[2048*2048]      (16777216)   sigma transposed
// total 17,080,832 B

// ---------------------------------------------------------------------------
// Kernel 1 (fused): blocks 0..127 do per-token exact top-K activation;
// blocks 128..4223 transpose sigma into ST0. Independent work, one launch.
// ---------------------------------------------------------------------------
__global__ __launch_bounds__(256) void act_transpose_kernel(
    const int* __restrict__ tokens, const float* __restrict__ proj,
    const float* __restrict__ sigma, float* __restrict__ ST0,
    int* __restrict__ act_idx, int* __restrict__ act_cnt,
    int* __restrict__ occCnt, unsigned char* __restrict__ occList)
{
    __shared__ float tile[32][33];      // transpose path
    __shared__ float wcand[4][KK];      // act path
    __shared__ float thrS;
    __shared__ int   idxLDS[64];
    __shared__ int   cntS;

    const int bx  = blockIdx.x;
    const int tid = threadIdx.x;

    if (bx >= TT) {
        // ---- transpose: ST0[j][i] = sigma[i][j] ----
        const int bT = bx - TT;
        const int tx = tid & 31;
        const int ty = tid >> 5;
        const int x0 = (bT & 63) * 32;
        const int y0 = (bT >> 6) * 32;
        #pragma unroll
        for (int k = 0; k < 4; ++k)
            tile[ty + k * 8][tx] = sigma[(size_t)(y0 + ty + k * 8) * NV + x0 + tx];
        __syncthreads();
        #pragma unroll
        for (int k = 0; k < 4; ++k)
            ST0[(size_t)(x0 + ty + k * 8) * NV + y0 + tx] = tile[tx][ty + k * 8];
        return;
    }

    // ---- activation: exact top-K threshold (per-wave extract + 4-way merge) ----
    const int t    = bx;
    const int lane = tid & 63;
    const int wid  = tid >> 6;

    const float* __restrict__ row = proj + (size_t)tokens[t] * (size_t)NV;

    float v[8];
    #pragma unroll
    for (int r = 0; r < 8; ++r) v[r] = row[wid * 512 + r * 64 + lane];

    for (int it = 0; it < KK; ++it) {
        float lm = v[0];
        #pragma unroll
        for (int r = 1; r < 8; ++r) lm = fmaxf(lm, v[r]);
        #pragma unroll
        for (int off = 1; off < 64; off <<= 1) lm = fmaxf(lm, __shfl_xor(lm, off));
        bool has = false;
        #pragma unroll
        for (int r = 0; r < 8; ++r) has = has || (v[r] == lm);
        const unsigned long long m = __ballot(has);
        if (lane == (int)(__ffsll((long long)m) - 1)) {
            bool done = false;
            #pragma unroll
            for (int r = 0; r < 8; ++r)
                if (!done && v[r] == lm) { v[r] = -__builtin_inff(); done = true; }
        }
        if (lane == 0) wcand[wid][it] = lm;
    }
    __syncthreads();

    if (tid == 0) {
        int p0 = 0, p1 = 0, p2 = 0, p3 = 0;
        float th = 0.0f;
        for (int k = 0; k < KK; ++k) {
            float bv = -__builtin_inff(); int bw = 0;
            if (p0 < KK && wcand[0][p0] > bv) { bv = wcand[0][p0]; bw = 0; }
            if (p1 < KK && wcand[1][p1] > bv) { bv = wcand[1][p1]; bw = 1; }
            if (p2 < KK && wcand[2][p2] > bv) { bv = wcand[2][p2]; bw = 2; }
            if (p3 < KK && wcand[3][p3] > bv) { bv = wcand[3][p3]; bw = 3; }
            if      (bw == 0) ++p0;
            else if (bw == 1) ++p1;
            else if (bw == 2) ++p2;
            else              ++p3;
            th = bv;
        }
        thrS = th;
    }
    __syncthreads();
    const float thr = thrS;

    if (wid == 0) {
        int base = 0;
        for (int round = 0; round < NV / 64; ++round) {
            const int i = round * 64 + lane;
            const bool p = (row[i] >= thr);
            const unsigned long long mm = __ballot(p);
            const int pos = base + (int)__popcll(mm & ((1ull << lane) - 1ull));
            if (p && pos < 64) idxLDS[pos] = i;
            base += (int)__popcll(mm);
        }
        if (lane == 0) cntS = base < 64 ? base : 64;
    }
    __syncthreads();
    const int cnt = cntS;
    if (tid == 0) act_cnt[t] = cnt;
    if (tid < cnt) {
        const int j = idxLDS[tid];
        act_idx[t * 64 + tid] = j;
        const int slot = atomicAdd(&occCnt[j], 1);
        occList[j * 128 + slot] = (unsigned char)t;
    }
}

// ---------------------------------------------------------------------------
// Kernel 2: one block per step t. u8-packed counts in LDS; single fused
// coalesced pass over ST0 rows produces both base sum and clipped delta.
//   pred[i] = sum_{j in A_t} [ s + min(1-s, LR*c_t(i,j)) ],  s = ST0[j][i]
//   c_t(i,j) = #{s < t : j in A_s, i in A_{s+1}}   (<= 126, fits u8)
// Per-i accumulation kept as (sum s) + (sum delta), ascending jj — bit-exact
// vs the validated absmax-0.0 version.
// ---------------------------------------------------------------------------
__global__ __launch_bounds__(512) void tension_kernel(
    const float* __restrict__ ST0,
    const int* __restrict__ act_idx, const int* __restrict__ act_cnt,
    const int* __restrict__ occCnt, const unsigned char* __restrict__ occList,
    const int* __restrict__ plast, float* __restrict__ out)
{
    const int t    = blockIdx.x;       // 0..126
    const int tid  = threadIdx.x;      // 0..511
    const int lane = tid & 63;
    const int wid  = tid >> 6;

    __shared__ float        predS[NV];          // 8 KB
    __shared__ unsigned int cnt8[CHK * 512];    // 40 KB: u8 counts, 4 per word
    __shared__ int          acur[64], anext[64];
    __shared__ float        wsum[8];

    const int ccur  = act_cnt[t];
    const int cnext = act_cnt[t + 1];
    if (tid < 64) {
        acur[tid]  = act_idx[t * 64 + tid];
        anext[tid] = act_idx[(t + 1) * 64 + tid];
    }

    const bool plas = (plast[0] != 0);

    float accx = 0.f, accy = 0.f, accz = 0.f, accw = 0.f;  // sum of s, i=4t+r
    float dx = 0.f, dy = 0.f, dz = 0.f, dw = 0.f;          // sum of delta

    for (int jc = 0; jc < ccur; jc += CHK) {
        const int je = (jc + CHK < ccur) ? jc + CHK : ccur;

        if (plas) {
            for (int e = tid; e < (je - jc) * 512; e += 512) cnt8[e] = 0u;
            __syncthreads();
            // count accumulation: c(i,j) over prior steps s<t with j in A_s
            for (int jj = jc; jj < je; ++jj) {
                const int j    = acur[jj];
                const int oc   = occCnt[j];
                const int base = (jj - jc) * 512;
                for (int p = tid; p < oc * 64; p += 512) {
                    const int o  = p >> 6;
                    const int ii = p & 63;
                    const int s  = (int)occList[j * 128 + o];
                    if (s < t) {
                        const int cs = act_cnt[s + 1];
                        if (ii < cs) {
                            const int i = act_idx[(s + 1) * 64 + ii];
                            atomicAdd(&cnt8[base + (i >> 2)],
                                      1u << (8 * (i & 3)));
                        }
                    }
                }
            }
        }
        __syncthreads();

        // fused coalesced pass: one float4 ST0-row read per thread per jj
        for (int jj = jc; jj < je; ++jj) {
            const float4 sv = *reinterpret_cast<const float4*>(
                ST0 + (size_t)acur[jj] * NV + 4 * tid);
            accx += sv.x; accy += sv.y; accz += sv.z; accw += sv.w;
            if (plas) {
                const unsigned w = cnt8[(jj - jc) * 512 + tid];
                if (w) {
                    const unsigned c0 =  w        & 255u;
                    const unsigned c1 = (w >> 8)  & 255u;
                    const unsigned c2 = (w >> 16) & 255u;
                    const unsigned c3 =  w >> 24;
                    if (c0) dx += fminf(1.0f - sv.x, LRC * (float)c0);
                    if (c1) dy += fminf(1.0f - sv.y, LRC * (float)c1);
                    if (c2) dz += fminf(1.0f - sv.z, LRC * (float)c2);
                    if (c3) dw += fminf(1.0f - sv.w, LRC * (float)c3);
                }
            }
        }
        __syncthreads();
    }

    predS[4 * tid + 0] = accx + dx;
    predS[4 * tid + 1] = accy + dy;
    predS[4 * tid + 2] = accz + dz;
    predS[4 * tid + 3] = accw + dw;
    __syncthreads();

    // norm^2 reduce over all 2048 (same order as validated version)
    float loc = 0.0f;
    #pragma unroll
    for (int r = 0; r < 4; ++r) { const float p = predS[r * 512 + tid]; loc += p * p; }
    #pragma unroll
    for (int off = 32; off; off >>= 1) loc += __shfl_down(loc, off);
    if (lane == 0) wsum[wid] = loc;
    __syncthreads();

    if (tid < 64) {
        float n2 = 0.0f;
        #pragma unroll
        for (int w = 0; w < 8; ++w) n2 += wsum[w];
        float d = (tid < cnext) ? predS[anext[tid]] : 0.0f;
        #pragma unroll
        for (int off = 32; off; off >>= 1) d += __shfl_down(d, off);
        if (tid == 0) {
            const float pn = sqrtf(n2);
            float tens;
            if (plas) {
                const float overlap = d / (pn * sqrtf((float)KK) + EPSC);
                tens = (pn > 0.0f) ? (1.0f - overlap) : 1.0f;
            } else {
                const float overlap = d / (pn * sqrtf((float)cnext) + EPSC);
                tens = 1.0f - overlap;
            }
            out[t] = tens;
        }
    }
}

// ---------------------------------------------------------------------------
extern "C" void kernel_launch(void* const* d_in, const int* in_sizes, int n_in,
                              void* d_out, int out_size, void* d_ws, size_t ws_size,
                              hipStream_t stream)
{
    const int*   tokens = (const int*)d_in[0];
    const float* proj   = (const float*)d_in[1];
    const float* sigma  = (const float*)d_in[2];
    const int*   plast  = (const int*)d_in[3];
    float*       out    = (float*)d_out;

    char* ws = (char*)d_ws;
    int*           act_idx = (int*)(ws + 0);
    int*           act_cnt = (int*)(ws + 32768);
    int*           occCnt  = (int*)(ws + 33280);
    unsigned char* occList = (unsigned char*)(ws + 41472);
    float*         ST0     = (float*)(ws + 303616);

    hipMemsetAsync(occCnt, 0, NV * sizeof(int), stream);
    act_transpose_kernel<<<TT + (NV / 32) * (NV / 32), 256, 0, stream>>>(
        tokens, proj, sigma, ST0, act_idx, act_cnt, occCnt, occList);
    tension_kernel<<<TM1, 512, 0, stream>>>(ST0, act_idx, act_cnt, occCnt,
                                            occList, plast, out);
}